// Round 10
// baseline (94.258 us; speedup 1.0000x reference)
//
#include <hip/hip_runtime.h>
#include <stdint.h>

// out[b,c] = <x_b/||x_b||, a_c/||a_c||>, B=16384, C=2048, D=1024, fp32 in/out.
// Pass 1: fp32 row-normalize -> bf16 into d_ws (single merged launch).
// Pass 2: bf16 MFMA GEMM, 256x256 tile, BK=64, 8 waves (2Mx4N), dbuf LDS,
//   4 phases/K-tile, prev-phase-consume pipeline == R6 (75.4us) schedule.
//   R10 change: ADDRESSING ONLY (attack VALUBusy 17.6%).
//   - All ds_read addresses = 8 precomputed per-lane base pointers +
//     compile-time offsets. Identity: swizzle input R&7 == rl&7 (lane-only,
//     since wr*128/m*16/64 are 0 mod 8) and (4+ts)^r7 == 4^(ts^r7), so
//     kk/m/n/half/parity all fold into immediates.
//   - K-loop unrolled x2 -> buffer parity is a template constant.
//   - Staging: per-lane voff folded into src base pointers; k0 advances via
//     scalar adds.
//   Schedule/guards identical to R6:
//     ph0: read bfN1[P]; stage B0(t+1)->B[P^1]; MFMA Q0(afA,bfN0)
//     ph1: read afB[P];  stage B1(t+1);         MFMA Q1(afA,bfN1); lgkm0+vm4
//     ph2: stage A0(t+2)->A[P]; MFMA Q2(afB,bfN1); read afA'[P^1]; vm2/vm0
//     ph3: stage A1(t+2);       MFMA Q3(afB,bfN0); read bfN0'[P^1]
//   Race rule: cross-wave read-ahead behind a barrier all waves reach after
//   their own counted vmcnt (vmcnt -> BAR -> read).

#define D_DIM 1024
#define N_DIM 2048
#define BMt 256
#define BNt 256
#define BKt 64
#define NKT 16      // D_DIM / BKt

typedef __bf16 bf16x8 __attribute__((ext_vector_type(8)));
typedef float  f32x4  __attribute__((ext_vector_type(4)));

__device__ __forceinline__ unsigned short f2bf(float f) {
    union { float f; uint32_t u; } v; v.f = f;
    uint32_t r = v.u + 0x7fffu + ((v.u >> 16) & 1u);  // RNE
    return (unsigned short)(r >> 16);
}

// One block per row (X rows then A rows): 256 threads x float4 = 1024 floats.
__global__ __launch_bounds__(256) void normalize_rows(
        const float* __restrict__ x, const float* __restrict__ a,
        unsigned short* __restrict__ xn, unsigned short* __restrict__ an,
        int Bn) {
    const int blk = blockIdx.x;
    const float* in = (blk < Bn) ? x : a;
    unsigned short* out = (blk < Bn) ? xn : an;
    const int row = (blk < Bn) ? blk : blk - Bn;
    const int t = threadIdx.x;
    const float4 v = ((const float4*)(in + (size_t)row * D_DIM))[t];
    float ss = v.x * v.x + v.y * v.y + v.z * v.z + v.w * v.w;
#pragma unroll
    for (int o = 1; o < 64; o <<= 1) ss += __shfl_xor(ss, o);
    __shared__ float red[4];
    if ((t & 63) == 0) red[t >> 6] = ss;
    __syncthreads();
    const float tot = red[0] + red[1] + red[2] + red[3];
    const float scale = 1.0f / fmaxf(sqrtf(tot), 1e-8f);
    ushort4 o;
    o.x = f2bf(v.x * scale);
    o.y = f2bf(v.y * scale);
    o.z = f2bf(v.z * scale);
    o.w = f2bf(v.w * scale);
    ((ushort4*)(out + (size_t)row * D_DIM))[t] = o;
}

__device__ __forceinline__ void gload_lds16(const void* g, void* l) {
    __builtin_amdgcn_global_load_lds(
        (const __attribute__((address_space(1))) void*)g,
        (__attribute__((address_space(3))) void*)l,
        16, 0, 0);
}

#define PH_BAR()   asm volatile("s_barrier" ::: "memory")
#define PH_LGKM0() asm volatile("s_waitcnt lgkmcnt(0)" ::: "memory")
#define VMCNT8()   asm volatile("s_waitcnt vmcnt(8)" ::: "memory")
#define VMCNT4()   asm volatile("s_waitcnt vmcnt(4)" ::: "memory")
#define VMCNT2()   asm volatile("s_waitcnt vmcnt(2)" ::: "memory")
#define VMCNT0()   asm volatile("s_waitcnt vmcnt(0)" ::: "memory")

// 16-MFMA quadrant
#define MFMA_Q(AF, BF, MOFF, NOFF)                                            \
    __builtin_amdgcn_s_setprio(1);                                            \
    _Pragma("unroll") for (int m = 0; m < 4; ++m)                             \
    _Pragma("unroll") for (int n = 0; n < 2; ++n)                             \
    _Pragma("unroll") for (int kk = 0; kk < 2; ++kk)                          \
        acc[(MOFF) + m][(NOFF) + n] = __builtin_amdgcn_mfma_f32_16x16x32_bf16(\
            AF[m][kk], BF[n][kk], acc[(MOFF) + m][(NOFF) + n], 0, 0, 0);      \
    __builtin_amdgcn_s_setprio(0);

// LDS byte regions (128 KiB total): A parity p at p*65536, B at 32768+p*65536.
// Half H of a region at +H*16384 bytes.

// pA[p][kk], pB[p][kk]: per-lane base pointers (precomputed once).
// A frag (quad q=0/1, m, kk): *(pA[p][kk] + q*8192 + m*2048)
// B frag (half h=0/1, n, kk): *(pB[p][kk] + h*4096 + n*2048)

template<int MODE, int P>
__device__ __forceinline__ void ktile(
        int t,
        const unsigned short* __restrict__ sA,   // A + rowA0*D + voff (per-lane)
        const unsigned short* __restrict__ sB,   // Bm + rowB0*D + voff
        char* lds0,                              // LDS byte base
        int dstW,                                // wid*1024 (byte)
        const char* const (&pA)[2][2], const char* const (&pB)[2][2],
        bf16x8 (&afA)[4][2], bf16x8 (&afB)[4][2],
        bf16x8 (&bfN0)[2][2], bf16x8 (&bfN1)[2][2],
        f32x4 (&acc)[8][4])
{
    // ---- ph0: read bfN1 (B[P] half1); stage B0(t+1)->B[P^1]; MFMA Q0
    PH_BAR();
#pragma unroll
    for (int n = 0; n < 2; ++n)
#pragma unroll
        for (int kk = 0; kk < 2; ++kk)
            bfN1[n][kk] = *(const bf16x8*)(pB[P][kk] + 4096 + n * 2048);
    if constexpr (MODE <= 1) {
        const int k1 = (t + 1) * BKt;
#pragma unroll
        for (int j = 0; j < 2; ++j)
            gload_lds16(sB + (j * 64) * D_DIM + k1,
                        lds0 + (32768 + (P ^ 1) * 65536) + j * 8192 + dstW);
    }
    MFMA_Q(afA, bfN0, 0, 0)

    // ---- ph1: read afB (A[P] quad1); stage B1(t+1); MFMA Q1; guards
    PH_BAR();
#pragma unroll
    for (int m = 0; m < 4; ++m)
#pragma unroll
        for (int kk = 0; kk < 2; ++kk)
            afB[m][kk] = *(const bf16x8*)(pA[P][kk] + 8192 + m * 2048);
    if constexpr (MODE <= 1) {
        const int k1 = (t + 1) * BKt;
#pragma unroll
        for (int j = 0; j < 2; ++j)
            gload_lds16(sB + (128 + j * 64) * D_DIM + k1,
                        lds0 + (32768 + (P ^ 1) * 65536) + 16384 + j * 8192 + dstW);
    }
    MFMA_Q(afA, bfN1, 0, 2)
    if constexpr (MODE <= 1) {
        PH_LGKM0();   // my A(t)/B(t) ds_reads drained before A(t+2) region reuse
        VMCNT4();     // A(t+1) landed (outstanding: B0',B1' = 4)
    }

    // ---- ph2: stage A0(t+2)->A[P]; MFMA Q2; read afA'(t+1); guard
    PH_BAR();
    if constexpr (MODE == 0) {
        const int k2 = (t + 2) * BKt;
#pragma unroll
        for (int j = 0; j < 2; ++j)
            gload_lds16(sA + (j * 64) * D_DIM + k2,
                        lds0 + (P * 65536) + j * 8192 + dstW);
    }
    MFMA_Q(afB, bfN1, 4, 2)
    if constexpr (MODE <= 1) {
#pragma unroll
        for (int m = 0; m < 4; ++m)
#pragma unroll
            for (int kk = 0; kk < 2; ++kk)
                afA[m][kk] = *(const bf16x8*)(pA[P ^ 1][kk] + m * 2048);
    }
    if constexpr (MODE == 0) VMCNT2();   // B(t+1) landed (leaves A0(t+2))
    if constexpr (MODE == 1) VMCNT0();   // drain B(15)

    // ---- ph3: stage A1(t+2); MFMA Q3; read bfN0'(t+1)
    PH_BAR();
    if constexpr (MODE == 0) {
        const int k2 = (t + 2) * BKt;
#pragma unroll
        for (int j = 0; j < 2; ++j)
            gload_lds16(sA + (128 + j * 64) * D_DIM + k2,
                        lds0 + (P * 65536) + 16384 + j * 8192 + dstW);
    }
    MFMA_Q(afB, bfN0, 4, 0)
    if constexpr (MODE <= 1) {
#pragma unroll
        for (int n = 0; n < 2; ++n)
#pragma unroll
            for (int kk = 0; kk < 2; ++kk)
                bfN0[n][kk] = *(const bf16x8*)(pB[P ^ 1][kk] + n * 2048);
    }
}

__global__ __launch_bounds__(512, 2) void gemm256(
        const unsigned short* __restrict__ A,
        const unsigned short* __restrict__ Bm,
        float* __restrict__ Cg)
{
    __shared__ unsigned short lds[65536];  // 128 KiB
    char* lds0 = (char*)lds;

    const int nwg = gridDim.x;          // 512
    const int cpx = nwg >> 3;           // 64
    const int wg  = ((int)blockIdx.x & 7) * cpx + ((int)blockIdx.x >> 3);
    const int bm  = wg >> 3;            // 0..63
    const int bn  = wg & 7;             // 0..7
    const int rowA0 = bm * BMt;
    const int rowB0 = bn * BNt;

    const int tid  = threadIdx.x;
    const int lane = tid & 63;
    const int wid  = tid >> 6;          // 0..7
    const int wr   = wid >> 2;          // 0..1 -> 128-row half
    const int wc   = wid & 3;           // 0..3 -> 64-col slice
    const int rl = lane & 15, ts = lane >> 4, r7 = rl & 7;

    // ---- precomputed per-lane ds_read base pointers (8) ----
    // byte addr = (rowbase+rl)*128 + ((kk*4+ts)^r7)<<4 + compile-time offsets
    const int swz0 = ((ts ^ r7) << 4);
    const int swz1 = (((4 + ts) ^ r7) << 4);
    const int aRow = (wr * 128 + rl) * 128;
    const int bRow = (wc * 64 + rl) * 128;
    const char* pA[2][2];
    const char* pB[2][2];
#pragma unroll
    for (int p = 0; p < 2; ++p) {
        pA[p][0] = lds0 + p * 65536 + aRow + swz0;
        pA[p][1] = lds0 + p * 65536 + aRow + swz1;
        pB[p][0] = lds0 + 32768 + p * 65536 + bRow + swz0;
        pB[p][1] = lds0 + 32768 + p * 65536 + bRow + swz1;
    }

    // ---- staging bases: per-lane voff folded into src pointers ----
    const int gcol = (((tid & 7) ^ ((tid >> 3) & 7)) << 3);  // pre-swizzled col
    const int grow = (tid >> 3);                              // 0..63
    const int voff = grow * D_DIM + gcol;
    const unsigned short* sA = A  + (size_t)rowA0 * D_DIM + voff;
    const unsigned short* sB = Bm + (size_t)rowB0 * D_DIM + voff;
    const int dstW = wid * 1024;  // byte offset of this wave's staging slot

    bf16x8 afA[4][2], afB[4][2], bfN0[2][2], bfN1[2][2];
    f32x4 acc[8][4] = {};

    // prologue: stage A(0)h0,h1; B(0)h0,h1; A(1)h0,h1 (12 loads);
    // vmcnt(4) -> A(0),B(0) landed -> BAR -> preload afA, bfN0 (parity 0).
    {
#pragma unroll
        for (int j = 0; j < 2; ++j) {
            gload_lds16(sA + (j * 64) * D_DIM,         lds0 + j * 8192 + dstW);
            gload_lds16(sA + (128 + j * 64) * D_DIM,   lds0 + 16384 + j * 8192 + dstW);
            gload_lds16(sB + (j * 64) * D_DIM,         lds0 + 32768 + j * 8192 + dstW);
            gload_lds16(sB + (128 + j * 64) * D_DIM,   lds0 + 32768 + 16384 + j * 8192 + dstW);
        }
#pragma unroll
        for (int j = 0; j < 2; ++j) {
            gload_lds16(sA + (j * 64) * D_DIM + BKt,       lds0 + 65536 + j * 8192 + dstW);
            gload_lds16(sA + (128 + j * 64) * D_DIM + BKt, lds0 + 65536 + 16384 + j * 8192 + dstW);
        }
        VMCNT4();
        PH_BAR();
#pragma unroll
        for (int m = 0; m < 4; ++m)
#pragma unroll
            for (int kk = 0; kk < 2; ++kk)
                afA[m][kk] = *(const bf16x8*)(pA[0][kk] + m * 2048);
#pragma unroll
        for (int n = 0; n < 2; ++n)
#pragma unroll
            for (int kk = 0; kk < 2; ++kk)
                bfN0[n][kk] = *(const bf16x8*)(pB[0][kk] + n * 2048);
    }

#pragma unroll 1
    for (int t = 0; t < NKT - 2; t += 2) {
        ktile<0, 0>(t,     sA, sB, lds0, dstW, pA, pB, afA, afB, bfN0, bfN1, acc);
        ktile<0, 1>(t + 1, sA, sB, lds0, dstW, pA, pB, afA, afB, bfN0, bfN1, acc);
    }
    ktile<1, 0>(NKT - 2, sA, sB, lds0, dstW, pA, pB, afA, afB, bfN0, bfN1, acc);
    ktile<2, 1>(NKT - 1, sA, sB, lds0, dstW, pA, pB, afA, afB, bfN0, bfN1, acc);

    // epilogue: C/D layout col=lane&15, row=(lane>>4)*4+j (m89-verified)
    const int crow0 = rowA0 + wr * 128 + (lane >> 4) * 4;
    const int ccol0 = rowB0 + wc * 64 + (lane & 15);
#pragma unroll
    for (int m = 0; m < 8; ++m)
#pragma unroll
        for (int n = 0; n < 4; ++n)
#pragma unroll
            for (int j = 0; j < 4; ++j)
                Cg[(size_t)(crow0 + m * 16 + j) * N_DIM + ccol0 + n * 16] = acc[m][n][j];
}

extern "C" void kernel_launch(void* const* d_in, const int* in_sizes, int n_in,
                              void* d_out, int out_size, void* d_ws, size_t ws_size,
                              hipStream_t stream) {
    const float* x = (const float*)d_in[0];   // [B, D]
    const float* a = (const float*)d_in[1];   // [C, D]
    float* out = (float*)d_out;               // [B, C]

    const int Bn = in_sizes[0] / D_DIM;  // 16384
    const int Cn = in_sizes[1] / D_DIM;  // 2048

    unsigned short* xn = (unsigned short*)d_ws;            // [B][D] bf16
    unsigned short* an = xn + (size_t)Bn * D_DIM;          // [C][D] bf16

    normalize_rows<<<Bn + Cn, 256, 0, stream>>>(x, a, xn, an, Bn);

    const int grid = (Bn / BMt) * (Cn / BNt);  // 64 * 8 = 512
    gemm256<<<grid, 512, 0, stream>>>(xn, an, out);
}